// Round 1
// baseline (1761.615 us; speedup 1.0000x reference)
//
#include <hip/hip_runtime.h>

// LIF_13984413516471
// B=128 batches, S=128 timesteps, H=128 hidden, K=8 neurons.
// Reference semantics: single (B,) accumulator s, sequential over
// (i, j, k) row-major; per step: s += x[b,i,j]; spike = s > th[k];
// out = spike ? s : 0; s -= out.  Outputs (B,S,K,H) fp32: outs then spikes.

#define NB 128
#define NS 128
#define NH 128
#define NK 8
#define NT (NS * NH)                 // 16384 time sub-positions per batch
#define OUTN ((size_t)NB * NS * NK * NH)  // 16,777,216 elements per output

// Pass 1: per-batch sequential chain; records s at entry of each t.
// 128 lanes total (one per batch) — latency-bound, but carries no
// output traffic; only the 8.4 MB state record.
__global__ void lif_chain(const float* __restrict__ x,   // [B][T]
                          const float* __restrict__ th,  // [K]
                          float* __restrict__ s_rec)     // [B][T]
{
    int b = blockIdx.x * 64 + threadIdx.x;
    if (b >= NB) return;
    float th0 = th[0], th1 = th[1], th2 = th[2], th3 = th[3];
    float th4 = th[4], th5 = th[5], th6 = th[6], th7 = th[7];
    const float* xb = x + (size_t)b * NT;
    float* sb = s_rec + (size_t)b * NT;
    float s = 0.0f;
    for (int t = 0; t < NT; ++t) {
        sb[t] = s;                 // entering state for this t
        float xv = xb[t];
        s += xv; s = (s > th0) ? 0.0f : s;
        s += xv; s = (s > th1) ? 0.0f : s;
        s += xv; s = (s > th2) ? 0.0f : s;
        s += xv; s = (s > th3) ? 0.0f : s;
        s += xv; s = (s > th4) ? 0.0f : s;
        s += xv; s = (s > th5) ? 0.0f : s;
        s += xv; s = (s > th6) ? 0.0f : s;
        s += xv; s = (s > th7) ? 0.0f : s;
    }
}

// Pass 2: fully parallel replay. Block = (b, i); thread = j.
// Reads s_rec[b][i*H+j] and x[b][i*H+j] (both coalesced in j),
// writes outs/spikes coalesced per k-plane. Bit-exact replay of the
// reference op order (adds + compares only; no contraction).
__global__ void lif_out(const float* __restrict__ x,     // [B][S*H]
                        const float* __restrict__ th,    // [K]
                        const float* __restrict__ s_rec, // [B][T]
                        float* __restrict__ out)         // outs | spikes
{
    int j = threadIdx.x;             // 0..127
    int i = blockIdx.x & (NS - 1);   // timestep
    int b = blockIdx.x >> 7;         // batch
    int t = i * NH + j;

    float s  = s_rec[(size_t)b * NT + t];
    float xv = x[(size_t)b * NT + t];

    float thr[NK];
#pragma unroll
    for (int k = 0; k < NK; ++k) thr[k] = th[k];

    float* o  = out + (((size_t)b * NS + i) * NK) * NH + j;
    float* sp = o + OUTN;

#pragma unroll
    for (int k = 0; k < NK; ++k) {
        s += xv;
        bool spike = s > thr[k];
        o[(size_t)k * NH]  = spike ? s : 0.0f;
        sp[(size_t)k * NH] = spike ? 1.0f : 0.0f;
        s = spike ? 0.0f : s;
    }
}

// Fallback if ws is too small: single-pass, scattered writes (slow, correct).
__global__ void lif_mono(const float* __restrict__ x,
                         const float* __restrict__ th,
                         float* __restrict__ out)
{
    int b = blockIdx.x * 64 + threadIdx.x;
    if (b >= NB) return;
    float thr[NK];
#pragma unroll
    for (int k = 0; k < NK; ++k) thr[k] = th[k];
    const float* xb = x + (size_t)b * NT;
    float s = 0.0f;
    for (int i = 0; i < NS; ++i) {
        for (int j = 0; j < NH; ++j) {
            float xv = xb[i * NH + j];
#pragma unroll
            for (int k = 0; k < NK; ++k) {
                s += xv;
                bool spike = s > thr[k];
                size_t idx = (((size_t)b * NS + i) * NK + k) * NH + j;
                out[idx]        = spike ? s : 0.0f;
                out[OUTN + idx] = spike ? 1.0f : 0.0f;
                s = spike ? 0.0f : s;
            }
        }
    }
}

extern "C" void kernel_launch(void* const* d_in, const int* in_sizes, int n_in,
                              void* d_out, int out_size, void* d_ws, size_t ws_size,
                              hipStream_t stream) {
    const float* x  = (const float*)d_in[0];   // (128,128,128) fp32
    const float* th = (const float*)d_in[1];   // (8,) fp32
    float* out = (float*)d_out;                // outs (16.7M) then spikes (16.7M)

    const size_t srec_bytes = (size_t)NB * NT * sizeof(float); // 8.4 MB
    if (ws_size >= srec_bytes) {
        float* s_rec = (float*)d_ws;
        lif_chain<<<dim3(2), dim3(64), 0, stream>>>(x, th, s_rec);
        lif_out<<<dim3(NB * NS), dim3(NH), 0, stream>>>(x, th, s_rec, out);
    } else {
        lif_mono<<<dim3(2), dim3(64), 0, stream>>>(x, th, out);
    }
}